// Round 1
// baseline (186.025 us; speedup 1.0000x reference)
//
#include <hip/hip_runtime.h>

#define B_ROWS 4096
#define N_ROWS 8192
#define DDIM   1024
#define DELTA_M 0.2f
#define EPSF    1e-8f

#define BM 128
#define BN 128
#define BK 32

typedef short bf16x8 __attribute__((ext_vector_type(8)));
typedef float f32x4 __attribute__((ext_vector_type(4)));

__device__ inline unsigned short f32_to_bf16(float f) {
    unsigned int u = __float_as_uint(f);
    u += 0x7FFFu + ((u >> 16) & 1u);   // round-to-nearest-even
    return (unsigned short)(u >> 16);
}

__device__ inline void load_lds16(const void* g, void* l) {
    __builtin_amdgcn_global_load_lds(
        (const __attribute__((address_space(1))) void*)g,
        (__attribute__((address_space(3))) void*)l,
        16, 0, 0);
}

// One block per row. Rows [0,B_ROWS): q/k pair -> qn bf16 + pos.
// Rows [B_ROWS, B_ROWS+N_ROWS): queue -> queuen bf16.
__global__ __launch_bounds__(256)
void norm_kernel(const float* __restrict__ q, const float* __restrict__ k,
                 const float* __restrict__ queue,
                 unsigned short* __restrict__ qn,
                 unsigned short* __restrict__ qun,
                 float* __restrict__ pos) {
    const int row  = blockIdx.x;
    const int tid  = threadIdx.x;
    const int lane = tid & 63;
    const int wave = tid >> 6;
    __shared__ float red[3][4];

    const bool isQ = row < B_ROWS;
    float4 v1, v2;
    if (isQ) {
        v1 = reinterpret_cast<const float4*>(q + (size_t)row * DDIM)[tid];
        v2 = reinterpret_cast<const float4*>(k + (size_t)row * DDIM)[tid];
    } else {
        v1 = reinterpret_cast<const float4*>(queue + (size_t)(row - B_ROWS) * DDIM)[tid];
        v2 = make_float4(0.f, 0.f, 0.f, 0.f);
    }
    float s11 = v1.x * v1.x + v1.y * v1.y + v1.z * v1.z + v1.w * v1.w;
    float s22 = v2.x * v2.x + v2.y * v2.y + v2.z * v2.z + v2.w * v2.w;
    float s12 = v1.x * v2.x + v1.y * v2.y + v1.z * v2.z + v1.w * v2.w;
    #pragma unroll
    for (int off = 32; off; off >>= 1) {
        s11 += __shfl_down(s11, off);
        s22 += __shfl_down(s22, off);
        s12 += __shfl_down(s12, off);
    }
    if (lane == 0) { red[0][wave] = s11; red[1][wave] = s22; red[2][wave] = s12; }
    __syncthreads();
    const float t11 = red[0][0] + red[0][1] + red[0][2] + red[0][3];
    const float inv1 = 1.0f / fmaxf(sqrtf(t11), EPSF);

    if (isQ) {
        const float t22 = red[1][0] + red[1][1] + red[1][2] + red[1][3];
        const float t12 = red[2][0] + red[2][1] + red[2][2] + red[2][3];
        const float inv2 = 1.0f / fmaxf(sqrtf(t22), EPSF);
        if (tid == 0) pos[row] = t12 * inv1 * inv2;
        ushort4 o;
        o.x = f32_to_bf16(v1.x * inv1);
        o.y = f32_to_bf16(v1.y * inv1);
        o.z = f32_to_bf16(v1.z * inv1);
        o.w = f32_to_bf16(v1.w * inv1);
        reinterpret_cast<ushort4*>(qn + (size_t)row * DDIM)[tid] = o;
    } else {
        ushort4 o;
        o.x = f32_to_bf16(v1.x * inv1);
        o.y = f32_to_bf16(v1.y * inv1);
        o.z = f32_to_bf16(v1.z * inv1);
        o.w = f32_to_bf16(v1.w * inv1);
        reinterpret_cast<ushort4*>(qun + (size_t)(row - B_ROWS) * DDIM)[tid] = o;
    }
}

// m97-structure GEMM: A[M,K] x B[N,K]^T, 128x128 tile, BK=32, 4 waves (2x2),
// each wave 64x64 via 4x4 fragments of mfma_f32_16x16x32_bf16.
// Fused epilogue: sum relu(DELTA - pos[row] + neg) -> atomicAdd.
__global__ __launch_bounds__(256, 2)
void gemm_hinge(const unsigned short* __restrict__ A,
                const unsigned short* __restrict__ Bq,
                const float* __restrict__ pos,
                float* __restrict__ out) {
    __shared__ unsigned short lA[BM * BK];
    __shared__ unsigned short lB[BN * BK];
    __shared__ float rbuf[4];

    const int tid  = threadIdx.x;
    const int lane = tid & 63;
    const int wave = tid >> 6;

    // XCD-aware bijective swizzle (grid = 2048, 2048 % 8 == 0)
    const int nBM = B_ROWS / BM;       // 32
    const int bid = blockIdx.x;
    const int cpx = gridDim.x >> 3;
    const int swz = (bid & 7) * cpx + (bid >> 3);
    const int bm = (swz % nBM) * BM;
    const int bn = (swz / nBM) * BN;

    const int wm = wave >> 1;          // 0..1
    const int wn = wave & 1;           // 0..1

    f32x4 acc[4][4];
    #pragma unroll
    for (int m = 0; m < 4; ++m)
        #pragma unroll
        for (int n = 0; n < 4; ++n)
            acc[m][n] = (f32x4){0.f, 0.f, 0.f, 0.f};

    // staging addressing: thread t loads 16B at row (t>>2), col (t&3)*8
    const int r = tid >> 2;
    const int c = tid & 3;
    const unsigned short* gA0 = A  + (size_t)(bm + r)      * DDIM + c * 8;
    const unsigned short* gA1 = A  + (size_t)(bm + r + 64) * DDIM + c * 8;
    const unsigned short* gB0 = Bq + (size_t)(bn + r)      * DDIM + c * 8;
    const unsigned short* gB1 = Bq + (size_t)(bn + r + 64) * DDIM + c * 8;
    unsigned short* lA0 = lA + tid * 8;
    unsigned short* lA1 = lA + 64 * BK + tid * 8;
    unsigned short* lB0 = lB + tid * 8;
    unsigned short* lB1 = lB + 64 * BK + tid * 8;

    // fragment read coords (A: row = lane&15, k-group = (lane>>4)*8; B same with col)
    const int arow = wm * 64 + (lane & 15);
    const int brow = wn * 64 + (lane & 15);
    const int kgrp = (lane >> 4) * 8;

    for (int k0 = 0; k0 < DDIM; k0 += BK) {
        load_lds16(gA0 + k0, lA0);
        load_lds16(gA1 + k0, lA1);
        load_lds16(gB0 + k0, lB0);
        load_lds16(gB1 + k0, lB1);
        __syncthreads();
        bf16x8 af[4], bf[4];
        #pragma unroll
        for (int m = 0; m < 4; ++m)
            af[m] = *reinterpret_cast<const bf16x8*>(&lA[(arow + m * 16) * BK + kgrp]);
        #pragma unroll
        for (int n = 0; n < 4; ++n)
            bf[n] = *reinterpret_cast<const bf16x8*>(&lB[(brow + n * 16) * BK + kgrp]);
        #pragma unroll
        for (int m = 0; m < 4; ++m)
            #pragma unroll
            for (int n = 0; n < 4; ++n)
                acc[m][n] = __builtin_amdgcn_mfma_f32_16x16x32_bf16(af[m], bf[n], acc[m][n], 0, 0, 0);
        __syncthreads();
    }

    // fused hinge epilogue.
    // C/D layout: col = lane&15, row = (lane>>4)*4 + j  [m89/m91 verified]
    float lsum = 0.f;
    const int rj = (lane >> 4) << 2;
    #pragma unroll
    for (int m = 0; m < 4; ++m) {
        float p[4];
        #pragma unroll
        for (int j = 0; j < 4; ++j)
            p[j] = pos[bm + wm * 64 + m * 16 + rj + j];
        #pragma unroll
        for (int n = 0; n < 4; ++n)
            #pragma unroll
            for (int j = 0; j < 4; ++j)
                lsum += fmaxf(DELTA_M - p[j] + acc[m][n][j], 0.f);
    }
    #pragma unroll
    for (int off = 32; off; off >>= 1) lsum += __shfl_down(lsum, off);
    if (lane == 0) rbuf[wave] = lsum;
    __syncthreads();
    if (tid == 0) atomicAdd(out, rbuf[0] + rbuf[1] + rbuf[2] + rbuf[3]);
}

extern "C" void kernel_launch(void* const* d_in, const int* in_sizes, int n_in,
                              void* d_out, int out_size, void* d_ws, size_t ws_size,
                              hipStream_t stream) {
    const float* q     = (const float*)d_in[0];
    const float* k     = (const float*)d_in[1];
    const float* queue = (const float*)d_in[2];
    float* out = (float*)d_out;

    // workspace: qn (8 MB) | queuen (16 MB) | pos (16 KB)
    unsigned short* qn  = (unsigned short*)d_ws;
    unsigned short* qun = qn + (size_t)B_ROWS * DDIM;
    float* pos = (float*)(qun + (size_t)N_ROWS * DDIM);

    hipMemsetAsync(d_out, 0, sizeof(float), stream);
    norm_kernel<<<B_ROWS + N_ROWS, 256, 0, stream>>>(q, k, queue, qn, qun, pos);
    gemm_hinge<<<(B_ROWS / BM) * (N_ROWS / BN), 256, 0, stream>>>(qn, qun, pos, out);
}

// Round 2
// 183.860 us; speedup vs baseline: 1.0118x; 1.0118x over previous
//
#include <hip/hip_runtime.h>

#define B_ROWS 4096
#define N_ROWS 8192
#define DDIM   1024
#define DELTA_M 0.2f
#define EPSF    1e-8f

#define BM 128
#define BN 128
#define BK 32

typedef short bf16x8 __attribute__((ext_vector_type(8)));
typedef float f32x4 __attribute__((ext_vector_type(4)));

__device__ inline unsigned short f32_to_bf16(float f) {
    unsigned int u = __float_as_uint(f);
    u += 0x7FFFu + ((u >> 16) & 1u);   // round-to-nearest-even
    return (unsigned short)(u >> 16);
}

__device__ inline void load_lds16(const void* g, void* l) {
    __builtin_amdgcn_global_load_lds(
        (const __attribute__((address_space(1))) void*)g,
        (__attribute__((address_space(3))) void*)l,
        16, 0, 0);
}

// Wave-per-row normalize. 4 waves/block, one row per wave, no LDS/barrier.
// Rows [0,B_ROWS): q/k pair -> qn bf16 + pos.  [B_ROWS,B_ROWS+N_ROWS): queue -> queuen.
__global__ __launch_bounds__(256)
void norm_kernel(const float* __restrict__ q, const float* __restrict__ k,
                 const float* __restrict__ queue,
                 unsigned short* __restrict__ qn,
                 unsigned short* __restrict__ qun,
                 float* __restrict__ pos) {
    const int tid  = threadIdx.x;
    const int lane = tid & 63;
    const int wave = tid >> 6;
    const int row  = blockIdx.x * 4 + wave;

    if (row < B_ROWS) {
        const float4* qr = reinterpret_cast<const float4*>(q + (size_t)row * DDIM);
        const float4* kr = reinterpret_cast<const float4*>(k + (size_t)row * DDIM);
        float4 a[4], b[4];
        #pragma unroll
        for (int j = 0; j < 4; ++j) a[j] = qr[lane + j * 64];
        #pragma unroll
        for (int j = 0; j < 4; ++j) b[j] = kr[lane + j * 64];
        float s11 = 0.f, s22 = 0.f, s12 = 0.f;
        #pragma unroll
        for (int j = 0; j < 4; ++j) {
            s11 += a[j].x * a[j].x + a[j].y * a[j].y + a[j].z * a[j].z + a[j].w * a[j].w;
            s22 += b[j].x * b[j].x + b[j].y * b[j].y + b[j].z * b[j].z + b[j].w * b[j].w;
            s12 += a[j].x * b[j].x + a[j].y * b[j].y + a[j].z * b[j].z + a[j].w * b[j].w;
        }
        #pragma unroll
        for (int off = 1; off < 64; off <<= 1) {
            s11 += __shfl_xor(s11, off);
            s22 += __shfl_xor(s22, off);
            s12 += __shfl_xor(s12, off);
        }
        const float inv1 = 1.0f / fmaxf(sqrtf(s11), EPSF);
        const float inv2 = 1.0f / fmaxf(sqrtf(s22), EPSF);
        if (lane == 0) pos[row] = s12 * inv1 * inv2;
        ushort4* orow = reinterpret_cast<ushort4*>(qn + (size_t)row * DDIM);
        #pragma unroll
        for (int j = 0; j < 4; ++j) {
            ushort4 o;
            o.x = f32_to_bf16(a[j].x * inv1);
            o.y = f32_to_bf16(a[j].y * inv1);
            o.z = f32_to_bf16(a[j].z * inv1);
            o.w = f32_to_bf16(a[j].w * inv1);
            orow[lane + j * 64] = o;
        }
    } else {
        const int r2 = row - B_ROWS;
        const float4* qr = reinterpret_cast<const float4*>(queue + (size_t)r2 * DDIM);
        float4 a[4];
        #pragma unroll
        for (int j = 0; j < 4; ++j) a[j] = qr[lane + j * 64];
        float s11 = 0.f;
        #pragma unroll
        for (int j = 0; j < 4; ++j)
            s11 += a[j].x * a[j].x + a[j].y * a[j].y + a[j].z * a[j].z + a[j].w * a[j].w;
        #pragma unroll
        for (int off = 1; off < 64; off <<= 1) s11 += __shfl_xor(s11, off);
        const float inv1 = 1.0f / fmaxf(sqrtf(s11), EPSF);
        ushort4* orow = reinterpret_cast<ushort4*>(qun + (size_t)r2 * DDIM);
        #pragma unroll
        for (int j = 0; j < 4; ++j) {
            ushort4 o;
            o.x = f32_to_bf16(a[j].x * inv1);
            o.y = f32_to_bf16(a[j].y * inv1);
            o.z = f32_to_bf16(a[j].z * inv1);
            o.w = f32_to_bf16(a[j].w * inv1);
            orow[lane + j * 64] = o;
        }
    }
}

// m97-structure GEMM: A[M,K] x B[N,K]^T, 128x128 tile, BK=32, 4 waves (2x2),
// each wave 64x64 via 4x4 fragments of mfma_f32_16x16x32_bf16.
// Fused epilogue: sum relu(DELTA - pos[row] + neg) -> atomicAdd.
__global__ __launch_bounds__(256, 2)
void gemm_hinge(const unsigned short* __restrict__ A,
                const unsigned short* __restrict__ Bq,
                const float* __restrict__ pos,
                float* __restrict__ out) {
    __shared__ unsigned short lA[BM * BK];
    __shared__ unsigned short lB[BN * BK];
    __shared__ float rbuf[4];

    const int tid  = threadIdx.x;
    const int lane = tid & 63;
    const int wave = tid >> 6;

    // XCD-aware bijective swizzle (grid = 2048, 2048 % 8 == 0)
    const int nBM = B_ROWS / BM;       // 32
    const int bid = blockIdx.x;
    const int cpx = gridDim.x >> 3;
    const int swz = (bid & 7) * cpx + (bid >> 3);
    const int bm = (swz % nBM) * BM;
    const int bn = (swz / nBM) * BN;

    const int wm = wave >> 1;          // 0..1
    const int wn = wave & 1;           // 0..1

    f32x4 acc[4][4];
    #pragma unroll
    for (int m = 0; m < 4; ++m)
        #pragma unroll
        for (int n = 0; n < 4; ++n)
            acc[m][n] = (f32x4){0.f, 0.f, 0.f, 0.f};

    // staging addressing: thread t loads 16B at row (t>>2), col (t&3)*8
    const int r = tid >> 2;
    const int c = tid & 3;
    const unsigned short* gA0 = A  + (size_t)(bm + r)      * DDIM + c * 8;
    const unsigned short* gA1 = A  + (size_t)(bm + r + 64) * DDIM + c * 8;
    const unsigned short* gB0 = Bq + (size_t)(bn + r)      * DDIM + c * 8;
    const unsigned short* gB1 = Bq + (size_t)(bn + r + 64) * DDIM + c * 8;
    unsigned short* lA0 = lA + tid * 8;
    unsigned short* lA1 = lA + 64 * BK + tid * 8;
    unsigned short* lB0 = lB + tid * 8;
    unsigned short* lB1 = lB + 64 * BK + tid * 8;

    // fragment read coords (A: row = lane&15, k-group = (lane>>4)*8; B same with col)
    const int arow = wm * 64 + (lane & 15);
    const int brow = wn * 64 + (lane & 15);
    const int kgrp = (lane >> 4) * 8;

    for (int k0 = 0; k0 < DDIM; k0 += BK) {
        load_lds16(gA0 + k0, lA0);
        load_lds16(gA1 + k0, lA1);
        load_lds16(gB0 + k0, lB0);
        load_lds16(gB1 + k0, lB1);
        __syncthreads();
        bf16x8 af[4], bf[4];
        #pragma unroll
        for (int m = 0; m < 4; ++m)
            af[m] = *reinterpret_cast<const bf16x8*>(&lA[(arow + m * 16) * BK + kgrp]);
        #pragma unroll
        for (int n = 0; n < 4; ++n)
            bf[n] = *reinterpret_cast<const bf16x8*>(&lB[(brow + n * 16) * BK + kgrp]);
        #pragma unroll
        for (int m = 0; m < 4; ++m)
            #pragma unroll
            for (int n = 0; n < 4; ++n)
                acc[m][n] = __builtin_amdgcn_mfma_f32_16x16x32_bf16(af[m], bf[n], acc[m][n], 0, 0, 0);
        __syncthreads();
    }

    // fused hinge epilogue.
    // C/D layout: col = lane&15, row = (lane>>4)*4 + j  [m89/m91 verified]
    float lsum = 0.f;
    const int rj = (lane >> 4) << 2;
    #pragma unroll
    for (int m = 0; m < 4; ++m) {
        float p[4];
        #pragma unroll
        for (int j = 0; j < 4; ++j)
            p[j] = pos[bm + wm * 64 + m * 16 + rj + j];
        #pragma unroll
        for (int n = 0; n < 4; ++n)
            #pragma unroll
            for (int j = 0; j < 4; ++j)
                lsum += fmaxf(DELTA_M - p[j] + acc[m][n][j], 0.f);
    }
    #pragma unroll
    for (int off = 32; off; off >>= 1) lsum += __shfl_down(lsum, off);
    if (lane == 0) rbuf[wave] = lsum;
    __syncthreads();
    if (tid == 0) atomicAdd(out, rbuf[0] + rbuf[1] + rbuf[2] + rbuf[3]);
}

extern "C" void kernel_launch(void* const* d_in, const int* in_sizes, int n_in,
                              void* d_out, int out_size, void* d_ws, size_t ws_size,
                              hipStream_t stream) {
    const float* q     = (const float*)d_in[0];
    const float* k     = (const float*)d_in[1];
    const float* queue = (const float*)d_in[2];
    float* out = (float*)d_out;

    // workspace: qn (8 MB) | queuen (16 MB) | pos (16 KB)
    unsigned short* qn  = (unsigned short*)d_ws;
    unsigned short* qun = qn + (size_t)B_ROWS * DDIM;
    float* pos = (float*)(qun + (size_t)N_ROWS * DDIM);

    hipMemsetAsync(d_out, 0, sizeof(float), stream);
    norm_kernel<<<(B_ROWS + N_ROWS) / 4, 256, 0, stream>>>(q, k, queue, qn, qun, pos);
    gemm_hinge<<<(B_ROWS / BM) * (N_ROWS / BN), 256, 0, stream>>>(qn, qun, pos, out);
}

// Round 3
// 179.440 us; speedup vs baseline: 1.0367x; 1.0246x over previous
//
#include <hip/hip_runtime.h>

#define B_ROWS 4096
#define N_ROWS 8192
#define DDIM   1024
#define DELTA_M 0.2f
#define EPSF    1e-8f

#define BM 128
#define BN 128
#define BK 32
#define NT (DDIM / BK)

typedef short bf16x8 __attribute__((ext_vector_type(8)));
typedef float f32x4 __attribute__((ext_vector_type(4)));

__device__ inline unsigned short f32_to_bf16(float f) {
    unsigned int u = __float_as_uint(f);
    u += 0x7FFFu + ((u >> 16) & 1u);   // round-to-nearest-even
    return (unsigned short)(u >> 16);
}

__device__ inline void load_lds16(const void* g, void* l) {
    __builtin_amdgcn_global_load_lds(
        (const __attribute__((address_space(1))) void*)g,
        (__attribute__((address_space(3))) void*)l,
        16, 0, 0);
}

// Wave-per-row normalize. 4 waves/block, one row per wave, no LDS/barrier.
__global__ __launch_bounds__(256)
void norm_kernel(const float* __restrict__ q, const float* __restrict__ k,
                 const float* __restrict__ queue,
                 unsigned short* __restrict__ qn,
                 unsigned short* __restrict__ qun,
                 float* __restrict__ pos) {
    const int tid  = threadIdx.x;
    const int lane = tid & 63;
    const int wave = tid >> 6;
    const int row  = blockIdx.x * 4 + wave;

    if (row < B_ROWS) {
        const float4* qr = reinterpret_cast<const float4*>(q + (size_t)row * DDIM);
        const float4* kr = reinterpret_cast<const float4*>(k + (size_t)row * DDIM);
        float4 a[4], b[4];
        #pragma unroll
        for (int j = 0; j < 4; ++j) a[j] = qr[lane + j * 64];
        #pragma unroll
        for (int j = 0; j < 4; ++j) b[j] = kr[lane + j * 64];
        float s11 = 0.f, s22 = 0.f, s12 = 0.f;
        #pragma unroll
        for (int j = 0; j < 4; ++j) {
            s11 += a[j].x * a[j].x + a[j].y * a[j].y + a[j].z * a[j].z + a[j].w * a[j].w;
            s22 += b[j].x * b[j].x + b[j].y * b[j].y + b[j].z * b[j].z + b[j].w * b[j].w;
            s12 += a[j].x * b[j].x + a[j].y * b[j].y + a[j].z * b[j].z + a[j].w * b[j].w;
        }
        #pragma unroll
        for (int off = 1; off < 64; off <<= 1) {
            s11 += __shfl_xor(s11, off);
            s22 += __shfl_xor(s22, off);
            s12 += __shfl_xor(s12, off);
        }
        const float inv1 = 1.0f / fmaxf(sqrtf(s11), EPSF);
        const float inv2 = 1.0f / fmaxf(sqrtf(s22), EPSF);
        if (lane == 0) pos[row] = s12 * inv1 * inv2;
        ushort4* orow = reinterpret_cast<ushort4*>(qn + (size_t)row * DDIM);
        #pragma unroll
        for (int j = 0; j < 4; ++j) {
            ushort4 o;
            o.x = f32_to_bf16(a[j].x * inv1);
            o.y = f32_to_bf16(a[j].y * inv1);
            o.z = f32_to_bf16(a[j].z * inv1);
            o.w = f32_to_bf16(a[j].w * inv1);
            orow[lane + j * 64] = o;
        }
    } else {
        const int r2 = row - B_ROWS;
        const float4* qr = reinterpret_cast<const float4*>(queue + (size_t)r2 * DDIM);
        float4 a[4];
        #pragma unroll
        for (int j = 0; j < 4; ++j) a[j] = qr[lane + j * 64];
        float s11 = 0.f;
        #pragma unroll
        for (int j = 0; j < 4; ++j)
            s11 += a[j].x * a[j].x + a[j].y * a[j].y + a[j].z * a[j].z + a[j].w * a[j].w;
        #pragma unroll
        for (int off = 1; off < 64; off <<= 1) s11 += __shfl_xor(s11, off);
        const float inv1 = 1.0f / fmaxf(sqrtf(s11), EPSF);
        ushort4* orow = reinterpret_cast<ushort4*>(qun + (size_t)r2 * DDIM);
        #pragma unroll
        for (int j = 0; j < 4; ++j) {
            ushort4 o;
            o.x = f32_to_bf16(a[j].x * inv1);
            o.y = f32_to_bf16(a[j].y * inv1);
            o.z = f32_to_bf16(a[j].z * inv1);
            o.w = f32_to_bf16(a[j].w * inv1);
            orow[lane + j * 64] = o;
        }
    }
}

// 128x128 GEMM, double-buffered LDS, 2-tile-deep counted-vmcnt pipeline.
// Per K-step: ds_read frags -> lgkmcnt(0) -> barrier -> issue tile t+2 into
// just-freed buffer -> MFMA -> vmcnt(4) (tile t+1 landed, t+2 in flight) -> barrier.
// Raw s_barrier throughout (no __syncthreads drain). Fused hinge epilogue.
__global__ __launch_bounds__(256, 2)
void gemm_hinge(const unsigned short* __restrict__ A,
                const unsigned short* __restrict__ Bq,
                const float* __restrict__ pos,
                float* __restrict__ out) {
    __shared__ unsigned short lA[2 * BM * BK];
    __shared__ unsigned short lB[2 * BN * BK];
    __shared__ float rbuf[4];

    const int tid  = threadIdx.x;
    const int lane = tid & 63;
    const int wave = tid >> 6;

    // XCD-aware bijective swizzle (grid = 2048, 2048 % 8 == 0)
    const int nBM = B_ROWS / BM;       // 32
    const int bid = blockIdx.x;
    const int cpx = gridDim.x >> 3;
    const int swz = (bid & 7) * cpx + (bid >> 3);
    const int bm = (swz % nBM) * BM;
    const int bn = (swz / nBM) * BN;

    const int wm = wave >> 1;          // 0..1
    const int wn = wave & 1;           // 0..1

    f32x4 acc[4][4];
    #pragma unroll
    for (int m = 0; m < 4; ++m)
        #pragma unroll
        for (int n = 0; n < 4; ++n)
            acc[m][n] = (f32x4){0.f, 0.f, 0.f, 0.f};

    // staging addressing: thread t loads 16B at row (t>>2), col (t&3)*8
    const int r = tid >> 2;
    const int c = tid & 3;
    const unsigned short* gA0 = A  + (size_t)(bm + r)      * DDIM + c * 8;
    const unsigned short* gA1 = A  + (size_t)(bm + r + 64) * DDIM + c * 8;
    const unsigned short* gB0 = Bq + (size_t)(bn + r)      * DDIM + c * 8;
    const unsigned short* gB1 = Bq + (size_t)(bn + r + 64) * DDIM + c * 8;

    // fragment read coords
    const int arow = wm * 64 + (lane & 15);
    const int brow = wn * 64 + (lane & 15);
    const int kgrp = (lane >> 4) * 8;

    // ---- prologue: stage tile 0 -> buf0, tile 1 -> buf1 ----
    {
        unsigned short* dA = lA;               // buf0
        unsigned short* dB = lB;
        load_lds16(gA0, dA + tid * 8);
        load_lds16(gA1, dA + 64 * BK + tid * 8);
        load_lds16(gB0, dB + tid * 8);
        load_lds16(gB1, dB + 64 * BK + tid * 8);
        dA = lA + BM * BK;                     // buf1
        dB = lB + BN * BK;
        load_lds16(gA0 + BK, dA + tid * 8);
        load_lds16(gA1 + BK, dA + 64 * BK + tid * 8);
        load_lds16(gB0 + BK, dB + tid * 8);
        load_lds16(gB1 + BK, dB + 64 * BK + tid * 8);
    }
    asm volatile("s_waitcnt vmcnt(4)" ::: "memory");   // tile 0 landed
    __builtin_amdgcn_sched_barrier(0);
    __builtin_amdgcn_s_barrier();
    __builtin_amdgcn_sched_barrier(0);

    for (int t = 0; t < NT; ++t) {
        const int cur = t & 1;
        const unsigned short* lAc = lA + cur * (BM * BK);
        const unsigned short* lBc = lB + cur * (BN * BK);

        bf16x8 af[4], bf[4];
        #pragma unroll
        for (int m = 0; m < 4; ++m)
            af[m] = *reinterpret_cast<const bf16x8*>(&lAc[(arow + m * 16) * BK + kgrp]);
        #pragma unroll
        for (int n = 0; n < 4; ++n)
            bf[n] = *reinterpret_cast<const bf16x8*>(&lBc[(brow + n * 16) * BK + kgrp]);

        // all my reads of buf[cur] done; barrier => all waves' reads done
        asm volatile("s_waitcnt lgkmcnt(0)" ::: "memory");
        __builtin_amdgcn_sched_barrier(0);
        __builtin_amdgcn_s_barrier();
        __builtin_amdgcn_sched_barrier(0);

        // stage tile t+2 into the buffer we just finished reading
        if (t + 2 < NT) {
            const int k0 = (t + 2) * BK;
            unsigned short* dA = lA + cur * (BM * BK);
            unsigned short* dB = lB + cur * (BN * BK);
            load_lds16(gA0 + k0, dA + tid * 8);
            load_lds16(gA1 + k0, dA + 64 * BK + tid * 8);
            load_lds16(gB0 + k0, dB + tid * 8);
            load_lds16(gB1 + k0, dB + 64 * BK + tid * 8);
        }

        #pragma unroll
        for (int m = 0; m < 4; ++m)
            #pragma unroll
            for (int n = 0; n < 4; ++n)
                acc[m][n] = __builtin_amdgcn_mfma_f32_16x16x32_bf16(af[m], bf[n], acc[m][n], 0, 0, 0);

        if (t < NT - 1) {
            // wait for tile t+1 only; leave t+2's 4 loads in flight
            if (t + 2 < NT) {
                asm volatile("s_waitcnt vmcnt(4)" ::: "memory");
            } else {
                asm volatile("s_waitcnt vmcnt(0)" ::: "memory");
            }
            __builtin_amdgcn_sched_barrier(0);
            __builtin_amdgcn_s_barrier();
            __builtin_amdgcn_sched_barrier(0);
        }
    }

    // fused hinge epilogue. C/D layout: col = lane&15, row = (lane>>4)*4 + j
    float lsum = 0.f;
    const int rj = (lane >> 4) << 2;
    #pragma unroll
    for (int m = 0; m < 4; ++m) {
        float p[4];
        #pragma unroll
        for (int j = 0; j < 4; ++j)
            p[j] = pos[bm + wm * 64 + m * 16 + rj + j];
        #pragma unroll
        for (int n = 0; n < 4; ++n)
            #pragma unroll
            for (int j = 0; j < 4; ++j)
                lsum += fmaxf(DELTA_M - p[j] + acc[m][n][j], 0.f);
    }
    #pragma unroll
    for (int off = 32; off; off >>= 1) lsum += __shfl_down(lsum, off);
    if (lane == 0) rbuf[wave] = lsum;
    __syncthreads();
    if (tid == 0) atomicAdd(out, rbuf[0] + rbuf[1] + rbuf[2] + rbuf[3]);
}

extern "C" void kernel_launch(void* const* d_in, const int* in_sizes, int n_in,
                              void* d_out, int out_size, void* d_ws, size_t ws_size,
                              hipStream_t stream) {
    const float* q     = (const float*)d_in[0];
    const float* k     = (const float*)d_in[1];
    const float* queue = (const float*)d_in[2];
    float* out = (float*)d_out;

    // workspace: qn (8 MB) | queuen (16 MB) | pos (16 KB)
    unsigned short* qn  = (unsigned short*)d_ws;
    unsigned short* qun = qn + (size_t)B_ROWS * DDIM;
    float* pos = (float*)(qun + (size_t)N_ROWS * DDIM);

    hipMemsetAsync(d_out, 0, sizeof(float), stream);
    norm_kernel<<<(B_ROWS + N_ROWS) / 4, 256, 0, stream>>>(q, k, queue, qn, qun, pos);
    gemm_hinge<<<(B_ROWS / BM) * (N_ROWS / BN), 256, 0, stream>>>(qn, qun, pos, out);
}

// Round 4
// 163.349 us; speedup vs baseline: 1.1388x; 1.0985x over previous
//
#include <hip/hip_runtime.h>

#define B_ROWS 4096
#define N_ROWS 8192
#define DDIM   1024
#define DELTA_M 0.2f
#define EPSF    1e-8f

#define BK2 64   // K-tile
#define NT2 (DDIM / BK2)   // 16 K-tiles

typedef short bf16x8 __attribute__((ext_vector_type(8)));
typedef float f32x4 __attribute__((ext_vector_type(4)));

__device__ inline unsigned short f32_to_bf16(float f) {
    unsigned int u = __float_as_uint(f);
    u += 0x7FFFu + ((u >> 16) & 1u);   // round-to-nearest-even
    return (unsigned short)(u >> 16);
}

__device__ inline void load_lds16(const void* g, void* l) {
    __builtin_amdgcn_global_load_lds(
        (const __attribute__((address_space(1))) void*)g,
        (__attribute__((address_space(3))) void*)l,
        16, 0, 0);
}

template<int N> __device__ __forceinline__ void vmwait() {
    if constexpr (N == 10) asm volatile("s_waitcnt vmcnt(10)" ::: "memory");
    else if constexpr (N == 8) asm volatile("s_waitcnt vmcnt(8)" ::: "memory");
    else if constexpr (N == 4) asm volatile("s_waitcnt vmcnt(4)" ::: "memory");
    else if constexpr (N == 2) asm volatile("s_waitcnt vmcnt(2)" ::: "memory");
    else asm volatile("s_waitcnt vmcnt(0)" ::: "memory");
    __builtin_amdgcn_sched_barrier(0);   // rule #18
}

// ---------------- norm (unchanged from R2) ----------------
__global__ __launch_bounds__(256)
void norm_kernel(const float* __restrict__ q, const float* __restrict__ k,
                 const float* __restrict__ queue,
                 unsigned short* __restrict__ qn,
                 unsigned short* __restrict__ qun,
                 float* __restrict__ pos) {
    const int tid  = threadIdx.x;
    const int lane = tid & 63;
    const int wave = tid >> 6;
    const int row  = blockIdx.x * 4 + wave;

    if (row < B_ROWS) {
        const float4* qr = reinterpret_cast<const float4*>(q + (size_t)row * DDIM);
        const float4* kr = reinterpret_cast<const float4*>(k + (size_t)row * DDIM);
        float4 a[4], b[4];
        #pragma unroll
        for (int j = 0; j < 4; ++j) a[j] = qr[lane + j * 64];
        #pragma unroll
        for (int j = 0; j < 4; ++j) b[j] = kr[lane + j * 64];
        float s11 = 0.f, s22 = 0.f, s12 = 0.f;
        #pragma unroll
        for (int j = 0; j < 4; ++j) {
            s11 += a[j].x * a[j].x + a[j].y * a[j].y + a[j].z * a[j].z + a[j].w * a[j].w;
            s22 += b[j].x * b[j].x + b[j].y * b[j].y + b[j].z * b[j].z + b[j].w * b[j].w;
            s12 += a[j].x * b[j].x + a[j].y * b[j].y + a[j].z * b[j].z + a[j].w * b[j].w;
        }
        #pragma unroll
        for (int off = 1; off < 64; off <<= 1) {
            s11 += __shfl_xor(s11, off);
            s22 += __shfl_xor(s22, off);
            s12 += __shfl_xor(s12, off);
        }
        const float inv1 = 1.0f / fmaxf(sqrtf(s11), EPSF);
        const float inv2 = 1.0f / fmaxf(sqrtf(s22), EPSF);
        if (lane == 0) pos[row] = s12 * inv1 * inv2;
        ushort4* orow = reinterpret_cast<ushort4*>(qn + (size_t)row * DDIM);
        #pragma unroll
        for (int j = 0; j < 4; ++j) {
            ushort4 o;
            o.x = f32_to_bf16(a[j].x * inv1);
            o.y = f32_to_bf16(a[j].y * inv1);
            o.z = f32_to_bf16(a[j].z * inv1);
            o.w = f32_to_bf16(a[j].w * inv1);
            orow[lane + j * 64] = o;
        }
    } else {
        const int r2 = row - B_ROWS;
        const float4* qr = reinterpret_cast<const float4*>(queue + (size_t)r2 * DDIM);
        float4 a[4];
        #pragma unroll
        for (int j = 0; j < 4; ++j) a[j] = qr[lane + j * 64];
        float s11 = 0.f;
        #pragma unroll
        for (int j = 0; j < 4; ++j)
            s11 += a[j].x * a[j].x + a[j].y * a[j].y + a[j].z * a[j].z + a[j].w * a[j].w;
        #pragma unroll
        for (int off = 1; off < 64; off <<= 1) s11 += __shfl_xor(s11, off);
        const float inv1 = 1.0f / fmaxf(sqrtf(s11), EPSF);
        ushort4* orow = reinterpret_cast<ushort4*>(qun + (size_t)r2 * DDIM);
        #pragma unroll
        for (int j = 0; j < 4; ++j) {
            ushort4 o;
            o.x = f32_to_bf16(a[j].x * inv1);
            o.y = f32_to_bf16(a[j].y * inv1);
            o.z = f32_to_bf16(a[j].z * inv1);
            o.w = f32_to_bf16(a[j].w * inv1);
            orow[lane + j * 64] = o;
        }
    }
}

// ---------------- 8-phase 256x256 GEMM + fused hinge ----------------
// LDS map (bytes): A[par][half] at par*32768 + half*16384; B at +65536.
// Each 16KB half-region: logical [128 rows][64 k] bf16, st_16x32 swizzled:
//   phys = logical ^ (((logical>>9)&1)<<5)  (involution; 16B-chunk-preserving).
// Staging: linear gload_lds dest d = t*16 + j*8192; source = logical elem at
//   swz(d)  (rule #21: linear dest + inverse-swizzled source + swizzled read).
// Window T (4 phases), quadrant order (mh,nh) = (0,0),(0,1),(1,1),(1,0):
//   LDS half last-read: Ah0@P0, Bh0@P0 (held in regs for P3), Bh1@P1, Ah1@P2.
//   Stage slots (1 half/phase): P0:(T+1).Ah1  P1:(T+2).Ah0  P2:(T+2).Bh0  P3:(T+2).Bh1
//   -> every overwrite is >=1 phase (barrier-separated) after last read. Proven safe.
// Per-thread issue order is uniform => counted vmcnt sound:
//   entry(T): retire T.Ah0,Bh0 -> 5 younger slots -> vmcnt(10)   [T=15: 2 slots -> 4]
//   end-P0:  retire T.Bh1     -> 5 younger slots -> vmcnt(10)   [T=15: 1 slot -> 2]
//   end-P1:  retire T.Ah1     -> 5 younger slots -> vmcnt(10)   [T=14: 4 -> 8; T=15: 0]
__device__ __forceinline__ void stage2(const unsigned short* M, int rowBase, int k0,
                                       unsigned char* region,
                                       int sr0, int sc0, int sr1, int sc1, int t16) {
    load_lds16(M + (size_t)(rowBase + sr0) * DDIM + k0 + sc0, region + t16);
    load_lds16(M + (size_t)(rowBase + sr1) * DDIM + k0 + sc1, region + 8192 + t16);
}

template<bool S1, bool S2, int WP0, int WP1, int WNEXT>
__device__ __forceinline__ void gemm_window(
    int T, unsigned char* lds,
    const unsigned short* A, const unsigned short* Bq,
    int bm, int bn, int wr, int wc, int aLane,
    int sr0, int sc0, int sr1, int sc1, int t16,
    f32x4 (&acc)[2][2][4][2]) {

    const int par = T & 1;
    const int pA0 = par * 32768;
    const int pA1 = pA0 + 16384;
    const int pB0 = 65536 + par * 32768;
    const int pB1 = pB0 + 16384;

    bf16x8 a[4][2], b0[2][2], b1[2][2];

    // ---- P0: read Ah0 + Bh0; stage (T+1).Ah1; MFMA quad (0,0) ----
    #pragma unroll
    for (int fm = 0; fm < 4; ++fm)
        #pragma unroll
        for (int ks = 0; ks < 2; ++ks)
            a[fm][ks] = *reinterpret_cast<const bf16x8*>(
                &lds[pA0 + wr * 8192 + fm * 2048 + ks * 64 + aLane]);
    #pragma unroll
    for (int fn = 0; fn < 2; ++fn)
        #pragma unroll
        for (int ks = 0; ks < 2; ++ks)
            b0[fn][ks] = *reinterpret_cast<const bf16x8*>(
                &lds[pB0 + wc * 4096 + fn * 2048 + ks * 64 + aLane]);
    if (S1)
        stage2(A, bm + 128, (T + 1) * BK2, lds + ((par ^ 1) * 32768 + 16384),
               sr0, sc0, sr1, sc1, t16);
    __builtin_amdgcn_s_barrier();
    asm volatile("s_waitcnt lgkmcnt(0)" ::: "memory");
    __builtin_amdgcn_sched_barrier(0);
    __builtin_amdgcn_s_setprio(1);
    #pragma unroll
    for (int fm = 0; fm < 4; ++fm)
        #pragma unroll
        for (int fn = 0; fn < 2; ++fn)
            #pragma unroll
            for (int ks = 0; ks < 2; ++ks)
                acc[0][0][fm][fn] = __builtin_amdgcn_mfma_f32_16x16x32_bf16(
                    a[fm][ks], b0[fn][ks], acc[0][0][fm][fn], 0, 0, 0);
    __builtin_amdgcn_s_setprio(0);
    vmwait<WP0>();
    __builtin_amdgcn_s_barrier();

    // ---- P1: read Bh1; stage (T+2).Ah0; MFMA quad (0,1) ----
    #pragma unroll
    for (int fn = 0; fn < 2; ++fn)
        #pragma unroll
        for (int ks = 0; ks < 2; ++ks)
            b1[fn][ks] = *reinterpret_cast<const bf16x8*>(
                &lds[pB1 + wc * 4096 + fn * 2048 + ks * 64 + aLane]);
    if (S2)
        stage2(A, bm, (T + 2) * BK2, lds + pA0, sr0, sc0, sr1, sc1, t16);
    __builtin_amdgcn_s_barrier();
    asm volatile("s_waitcnt lgkmcnt(0)" ::: "memory");
    __builtin_amdgcn_sched_barrier(0);
    __builtin_amdgcn_s_setprio(1);
    #pragma unroll
    for (int fm = 0; fm < 4; ++fm)
        #pragma unroll
        for (int fn = 0; fn < 2; ++fn)
            #pragma unroll
            for (int ks = 0; ks < 2; ++ks)
                acc[0][1][fm][fn] = __builtin_amdgcn_mfma_f32_16x16x32_bf16(
                    a[fm][ks], b1[fn][ks], acc[0][1][fm][fn], 0, 0, 0);
    __builtin_amdgcn_s_setprio(0);
    vmwait<WP1>();
    __builtin_amdgcn_s_barrier();

    // ---- P2: read Ah1; stage (T+2).Bh0; MFMA quad (1,1) ----
    #pragma unroll
    for (int fm = 0; fm < 4; ++fm)
        #pragma unroll
        for (int ks = 0; ks < 2; ++ks)
            a[fm][ks] = *reinterpret_cast<const bf16x8*>(
                &lds[pA1 + wr * 8192 + fm * 2048 + ks * 64 + aLane]);
    if (S2)
        stage2(Bq, bn, (T + 2) * BK2, lds + pB0, sr0, sc0, sr1, sc1, t16);
    __builtin_amdgcn_s_barrier();
    asm volatile("s_waitcnt lgkmcnt(0)" ::: "memory");
    __builtin_amdgcn_sched_barrier(0);
    __builtin_amdgcn_s_setprio(1);
    #pragma unroll
    for (int fm = 0; fm < 4; ++fm)
        #pragma unroll
        for (int fn = 0; fn < 2; ++fn)
            #pragma unroll
            for (int ks = 0; ks < 2; ++ks)
                acc[1][1][fm][fn] = __builtin_amdgcn_mfma_f32_16x16x32_bf16(
                    a[fm][ks], b1[fn][ks], acc[1][1][fm][fn], 0, 0, 0);
    __builtin_amdgcn_s_setprio(0);
    __builtin_amdgcn_s_barrier();

    // ---- P3: no reads (b0 held in regs); stage (T+2).Bh1; MFMA quad (1,0) ----
    if (S2)
        stage2(Bq, bn + 128, (T + 2) * BK2, lds + pB1, sr0, sc0, sr1, sc1, t16);
    __builtin_amdgcn_s_barrier();
    __builtin_amdgcn_s_setprio(1);
    #pragma unroll
    for (int fm = 0; fm < 4; ++fm)
        #pragma unroll
        for (int fn = 0; fn < 2; ++fn)
            #pragma unroll
            for (int ks = 0; ks < 2; ++ks)
                acc[1][0][fm][fn] = __builtin_amdgcn_mfma_f32_16x16x32_bf16(
                    a[fm][ks], b0[fn][ks], acc[1][0][fm][fn], 0, 0, 0);
    __builtin_amdgcn_s_setprio(0);
    vmwait<WNEXT>();
    __builtin_amdgcn_s_barrier();
}

__global__ __launch_bounds__(512, 2)
void gemm_hinge(const unsigned short* __restrict__ A,
                const unsigned short* __restrict__ Bq,
                const float* __restrict__ pos,
                float* __restrict__ out) {
    __shared__ __align__(16) unsigned char lds[131072];

    const int tid  = threadIdx.x;
    const int lane = tid & 63;
    const int wave = tid >> 6;

    // XCD swizzle: grid 512, 512 % 8 == 0
    const int bid = blockIdx.x;
    const int swz = (bid & 7) * (gridDim.x >> 3) + (bid >> 3);
    const int bm = (swz & 15) * 256;   // 16 M-blocks
    const int bn = (swz >> 4) * 256;   // 32 N-blocks

    const int wr = wave >> 2, wc = wave & 3;
    const int ln15 = lane & 15, kq = lane >> 4;
    // swizzled read lane term (bit9 of logical addr == (ln15>>2)&1; proof in header)
    const int aLane = (ln15 * 128 + kq * 16) ^ ((((ln15 >> 2) & 1)) << 5);
    const int t16 = tid * 16;
    const int d0 = t16, d1 = t16 + 8192;
    const int l0 = d0 ^ (((d0 >> 9) & 1) << 5);
    const int l1 = d1 ^ (((d1 >> 9) & 1) << 5);
    const int sr0 = l0 >> 7, sc0 = (l0 & 127) >> 1;
    const int sr1 = l1 >> 7, sc1 = (l1 & 127) >> 1;

    f32x4 acc[2][2][4][2];
    #pragma unroll
    for (int a = 0; a < 2; ++a)
        #pragma unroll
        for (int b = 0; b < 2; ++b)
            #pragma unroll
            for (int c = 0; c < 4; ++c)
                #pragma unroll
                for (int d = 0; d < 2; ++d)
                    acc[a][b][c][d] = (f32x4){0.f, 0.f, 0.f, 0.f};

    // prologue: per-thread issue order 0.Ah0, 0.Bh0, 0.Bh1, 0.Ah1, 1.Ah0, 1.Bh0, 1.Bh1
    stage2(A,  bm,       0,   lds,                         sr0, sc0, sr1, sc1, t16);
    stage2(Bq, bn,       0,   lds + 65536,                 sr0, sc0, sr1, sc1, t16);
    stage2(Bq, bn + 128, 0,   lds + 65536 + 16384,         sr0, sc0, sr1, sc1, t16);
    stage2(A,  bm + 128, 0,   lds + 16384,                 sr0, sc0, sr1, sc1, t16);
    stage2(A,  bm,       BK2, lds + 32768,                 sr0, sc0, sr1, sc1, t16);
    stage2(Bq, bn,       BK2, lds + 65536 + 32768,         sr0, sc0, sr1, sc1, t16);
    stage2(Bq, bn + 128, BK2, lds + 65536 + 32768 + 16384, sr0, sc0, sr1, sc1, t16);
    vmwait<10>();                       // 0.Ah0 + 0.Bh0 landed
    __builtin_amdgcn_s_barrier();

    #pragma unroll 1
    for (int T = 0; T < 14; ++T)
        gemm_window<true, true, 10, 10, 10>(T, lds, A, Bq, bm, bn, wr, wc, aLane,
                                            sr0, sc0, sr1, sc1, t16, acc);
    gemm_window<true, false, 10, 8, 4>(14, lds, A, Bq, bm, bn, wr, wc, aLane,
                                       sr0, sc0, sr1, sc1, t16, acc);
    gemm_window<false, false, 2, 0, 0>(15, lds, A, Bq, bm, bn, wr, wc, aLane,
                                       sr0, sc0, sr1, sc1, t16, acc);

    // ---- fused hinge epilogue ----
    // C/D: col = bn + nh*128 + wc*32 + fn*16 + (lane&15); row = bm + mh*128 + wr*64 + fm*16 + kq*4 + j
    float lsum = 0.f;
    const int rj = kq * 4;
    #pragma unroll
    for (int mh = 0; mh < 2; ++mh)
        #pragma unroll
        for (int fm = 0; fm < 4; ++fm) {
            const float4 p4 = *reinterpret_cast<const float4*>(
                pos + bm + mh * 128 + wr * 64 + fm * 16 + rj);
            const float pj[4] = {p4.x, p4.y, p4.z, p4.w};
            #pragma unroll
            for (int nh = 0; nh < 2; ++nh)
                #pragma unroll
                for (int fn = 0; fn < 2; ++fn)
                    #pragma unroll
                    for (int j = 0; j < 4; ++j)
                        lsum += fmaxf(DELTA_M - pj[j] + acc[mh][nh][fm][fn][j], 0.f);
        }
    #pragma unroll
    for (int off = 32; off; off >>= 1) lsum += __shfl_down(lsum, off);
    __syncthreads();                    // LDS safe to reuse (all tiles consumed)
    float* red = reinterpret_cast<float*>(lds);
    if (lane == 0) red[wave] = lsum;
    __syncthreads();
    if (tid == 0) {
        float s = 0.f;
        #pragma unroll
        for (int w = 0; w < 8; ++w) s += red[w];
        atomicAdd(out, s);
    }
}

extern "C" void kernel_launch(void* const* d_in, const int* in_sizes, int n_in,
                              void* d_out, int out_size, void* d_ws, size_t ws_size,
                              hipStream_t stream) {
    const float* q     = (const float*)d_in[0];
    const float* k     = (const float*)d_in[1];
    const float* queue = (const float*)d_in[2];
    float* out = (float*)d_out;

    unsigned short* qn  = (unsigned short*)d_ws;
    unsigned short* qun = qn + (size_t)B_ROWS * DDIM;
    float* pos = (float*)(qun + (size_t)N_ROWS * DDIM);

    hipMemsetAsync(d_out, 0, sizeof(float), stream);
    norm_kernel<<<(B_ROWS + N_ROWS) / 4, 256, 0, stream>>>(q, k, queue, qn, qun, pos);
    gemm_hinge<<<(B_ROWS / 256) * (N_ROWS / 256), 512, 0, stream>>>(qn, qun, pos, out);
}

// Round 6
// 159.398 us; speedup vs baseline: 1.1670x; 1.0248x over previous
//
#include <hip/hip_runtime.h>

#define B_ROWS 4096
#define N_ROWS 8192
#define DDIM   1024
#define DELTA_M 0.2f
#define EPSF    1e-8f

#define BK2 64   // K-tile
#define NT2 (DDIM / BK2)   // 16 K-tiles

typedef short bf16x8 __attribute__((ext_vector_type(8)));
typedef float f32x4 __attribute__((ext_vector_type(4)));

__device__ inline unsigned short f32_to_bf16(float f) {
    unsigned int u = __float_as_uint(f);
    u += 0x7FFFu + ((u >> 16) & 1u);   // round-to-nearest-even
    return (unsigned short)(u >> 16);
}

__device__ inline void load_lds16(const void* g, void* l) {
    __builtin_amdgcn_global_load_lds(
        (const __attribute__((address_space(1))) void*)g,
        (__attribute__((address_space(3))) void*)l,
        16, 0, 0);
}

template<int N> __device__ __forceinline__ void vmwait() {
    if constexpr (N == 10) asm volatile("s_waitcnt vmcnt(10)" ::: "memory");
    else if constexpr (N == 8) asm volatile("s_waitcnt vmcnt(8)" ::: "memory");
    else if constexpr (N == 4) asm volatile("s_waitcnt vmcnt(4)" ::: "memory");
    else if constexpr (N == 2) asm volatile("s_waitcnt vmcnt(2)" ::: "memory");
    else asm volatile("s_waitcnt vmcnt(0)" ::: "memory");
    __builtin_amdgcn_sched_barrier(0);   // rule #18
}

// ---------------- norm (unchanged) ----------------
__global__ __launch_bounds__(256)
void norm_kernel(const float* __restrict__ q, const float* __restrict__ k,
                 const float* __restrict__ queue,
                 unsigned short* __restrict__ qn,
                 unsigned short* __restrict__ qun,
                 float* __restrict__ pos) {
    const int tid  = threadIdx.x;
    const int lane = tid & 63;
    const int wave = tid >> 6;
    const int row  = blockIdx.x * 4 + wave;

    if (row < B_ROWS) {
        const float4* qr = reinterpret_cast<const float4*>(q + (size_t)row * DDIM);
        const float4* kr = reinterpret_cast<const float4*>(k + (size_t)row * DDIM);
        float4 a[4], b[4];
        #pragma unroll
        for (int j = 0; j < 4; ++j) a[j] = qr[lane + j * 64];
        #pragma unroll
        for (int j = 0; j < 4; ++j) b[j] = kr[lane + j * 64];
        float s11 = 0.f, s22 = 0.f, s12 = 0.f;
        #pragma unroll
        for (int j = 0; j < 4; ++j) {
            s11 += a[j].x * a[j].x + a[j].y * a[j].y + a[j].z * a[j].z + a[j].w * a[j].w;
            s22 += b[j].x * b[j].x + b[j].y * b[j].y + b[j].z * b[j].z + b[j].w * b[j].w;
            s12 += a[j].x * b[j].x + a[j].y * b[j].y + a[j].z * b[j].z + a[j].w * b[j].w;
        }
        #pragma unroll
        for (int off = 1; off < 64; off <<= 1) {
            s11 += __shfl_xor(s11, off);
            s22 += __shfl_xor(s22, off);
            s12 += __shfl_xor(s12, off);
        }
        const float inv1 = 1.0f / fmaxf(sqrtf(s11), EPSF);
        const float inv2 = 1.0f / fmaxf(sqrtf(s22), EPSF);
        if (lane == 0) pos[row] = s12 * inv1 * inv2;
        ushort4* orow = reinterpret_cast<ushort4*>(qn + (size_t)row * DDIM);
        #pragma unroll
        for (int j = 0; j < 4; ++j) {
            ushort4 o;
            o.x = f32_to_bf16(a[j].x * inv1);
            o.y = f32_to_bf16(a[j].y * inv1);
            o.z = f32_to_bf16(a[j].z * inv1);
            o.w = f32_to_bf16(a[j].w * inv1);
            orow[lane + j * 64] = o;
        }
    } else {
        const int r2 = row - B_ROWS;
        const float4* qr = reinterpret_cast<const float4*>(queue + (size_t)r2 * DDIM);
        float4 a[4];
        #pragma unroll
        for (int j = 0; j < 4; ++j) a[j] = qr[lane + j * 64];
        float s11 = 0.f;
        #pragma unroll
        for (int j = 0; j < 4; ++j)
            s11 += a[j].x * a[j].x + a[j].y * a[j].y + a[j].z * a[j].z + a[j].w * a[j].w;
        #pragma unroll
        for (int off = 1; off < 64; off <<= 1) s11 += __shfl_xor(s11, off);
        const float inv1 = 1.0f / fmaxf(sqrtf(s11), EPSF);
        ushort4* orow = reinterpret_cast<ushort4*>(qun + (size_t)r2 * DDIM);
        #pragma unroll
        for (int j = 0; j < 4; ++j) {
            ushort4 o;
            o.x = f32_to_bf16(a[j].x * inv1);
            o.y = f32_to_bf16(a[j].y * inv1);
            o.z = f32_to_bf16(a[j].z * inv1);
            o.w = f32_to_bf16(a[j].w * inv1);
            orow[lane + j * 64] = o;
        }
    }
}

// ---------------- 8-phase 256x256 GEMM + fused hinge ----------------
// LDS map (bytes): A[par][half] at par*32768 + half*16384; B at +65536.
// Each 16KB half-region: logical [128 rows][64 k] bf16 (128B rows), swizzled
//   phys = logical ^ ((row & 7) << 4)   (row = byte>>7; involution; XOR hits
//   byte bits[6:4] = 16B-chunk index -> 8 rows spread across all 8 chunk cols;
//   fixes the R4 residual 8-way ds_read_b128 bank conflict).
// Staging (rule #21): linear gload_lds dest d; per-lane global source = logical
//   element at d ^ (((d>>7)&7)<<4).  Read side applies the same XOR.
// Window T (4 phases), quadrant order (mh,nh) = (0,0),(0,1),(1,1),(1,0):
//   Stage slots (1 half/phase): P0:(T+1).Ah1  P1:(T+2).Ah0  P2:(T+2).Bh0  P3:(T+2).Bh1
//   every overwrite is >=1 barrier-separated phase after last read (proof R3/R4).
// Counted vmcnt (per-thread issue order uniform):
//   steady: 10 / 10 / 10 ; T=14: 10 / 8 / 4 ; T=15: 2 / 0 / 0.
__device__ __forceinline__ void stage2(const unsigned short* M, int rowBase, int k0,
                                       unsigned char* region,
                                       int sr0, int sc0, int sr1, int sc1, int t16) {
    load_lds16(M + (size_t)(rowBase + sr0) * DDIM + k0 + sc0, region + t16);
    load_lds16(M + (size_t)(rowBase + sr1) * DDIM + k0 + sc1, region + 8192 + t16);
}

template<bool S1, bool S2, int WP0, int WP1, int WNEXT>
__device__ __forceinline__ void gemm_window(
    int T, unsigned char* lds,
    const unsigned short* A, const unsigned short* Bq,
    int bm, int bn, int wr, int wc, int aL0, int aL1,
    int sr0, int sc0, int sr1, int sc1, int t16,
    f32x4 (&acc)[2][2][4][2]) {

    const int par = T & 1;
    const int pA0 = par * 32768;
    const int pA1 = pA0 + 16384;
    const int pB0 = 65536 + par * 32768;
    const int pB1 = pB0 + 16384;

    bf16x8 a[4][2], b0[2][2], b1[2][2];

    // ---- P0: read Ah0 + Bh0; stage (T+1).Ah1; MFMA quad (0,0) ----
    #pragma unroll
    for (int fm = 0; fm < 4; ++fm)
        #pragma unroll
        for (int ks = 0; ks < 2; ++ks)
            a[fm][ks] = *reinterpret_cast<const bf16x8*>(
                &lds[pA0 + wr * 8192 + fm * 2048 + (ks == 0 ? aL0 : aL1)]);
    #pragma unroll
    for (int fn = 0; fn < 2; ++fn)
        #pragma unroll
        for (int ks = 0; ks < 2; ++ks)
            b0[fn][ks] = *reinterpret_cast<const bf16x8*>(
                &lds[pB0 + wc * 4096 + fn * 2048 + (ks == 0 ? aL0 : aL1)]);
    if (S1)
        stage2(A, bm + 128, (T + 1) * BK2, lds + ((par ^ 1) * 32768 + 16384),
               sr0, sc0, sr1, sc1, t16);
    __builtin_amdgcn_s_barrier();
    asm volatile("s_waitcnt lgkmcnt(0)" ::: "memory");
    __builtin_amdgcn_sched_barrier(0);
    __builtin_amdgcn_s_setprio(1);
    #pragma unroll
    for (int fm = 0; fm < 4; ++fm)
        #pragma unroll
        for (int fn = 0; fn < 2; ++fn)
            #pragma unroll
            for (int ks = 0; ks < 2; ++ks)
                acc[0][0][fm][fn] = __builtin_amdgcn_mfma_f32_16x16x32_bf16(
                    a[fm][ks], b0[fn][ks], acc[0][0][fm][fn], 0, 0, 0);
    __builtin_amdgcn_s_setprio(0);
    vmwait<WP0>();
    __builtin_amdgcn_s_barrier();

    // ---- P1: read Bh1; stage (T+2).Ah0; MFMA quad (0,1) ----
    #pragma unroll
    for (int fn = 0; fn < 2; ++fn)
        #pragma unroll
        for (int ks = 0; ks < 2; ++ks)
            b1[fn][ks] = *reinterpret_cast<const bf16x8*>(
                &lds[pB1 + wc * 4096 + fn * 2048 + (ks == 0 ? aL0 : aL1)]);
    if (S2)
        stage2(A, bm, (T + 2) * BK2, lds + pA0, sr0, sc0, sr1, sc1, t16);
    __builtin_amdgcn_s_barrier();
    asm volatile("s_waitcnt lgkmcnt(0)" ::: "memory");
    __builtin_amdgcn_sched_barrier(0);
    __builtin_amdgcn_s_setprio(1);
    #pragma unroll
    for (int fm = 0; fm < 4; ++fm)
        #pragma unroll
        for (int fn = 0; fn < 2; ++fn)
            #pragma unroll
            for (int ks = 0; ks < 2; ++ks)
                acc[0][1][fm][fn] = __builtin_amdgcn_mfma_f32_16x16x32_bf16(
                    a[fm][ks], b1[fn][ks], acc[0][1][fm][fn], 0, 0, 0);
    __builtin_amdgcn_s_setprio(0);
    vmwait<WP1>();
    __builtin_amdgcn_s_barrier();

    // ---- P2: read Ah1; stage (T+2).Bh0; MFMA quad (1,1) ----
    #pragma unroll
    for (int fm = 0; fm < 4; ++fm)
        #pragma unroll
        for (int ks = 0; ks < 2; ++ks)
            a[fm][ks] = *reinterpret_cast<const bf16x8*>(
                &lds[pA1 + wr * 8192 + fm * 2048 + (ks == 0 ? aL0 : aL1)]);
    if (S2)
        stage2(Bq, bn, (T + 2) * BK2, lds + pB0, sr0, sc0, sr1, sc1, t16);
    __builtin_amdgcn_s_barrier();
    asm volatile("s_waitcnt lgkmcnt(0)" ::: "memory");
    __builtin_amdgcn_sched_barrier(0);
    __builtin_amdgcn_s_setprio(1);
    #pragma unroll
    for (int fm = 0; fm < 4; ++fm)
        #pragma unroll
        for (int fn = 0; fn < 2; ++fn)
            #pragma unroll
            for (int ks = 0; ks < 2; ++ks)
                acc[1][1][fm][fn] = __builtin_amdgcn_mfma_f32_16x16x32_bf16(
                    a[fm][ks], b1[fn][ks], acc[1][1][fm][fn], 0, 0, 0);
    __builtin_amdgcn_s_setprio(0);
    __builtin_amdgcn_s_barrier();

    // ---- P3: no reads (b0 held in regs); stage (T+2).Bh1; MFMA quad (1,0) ----
    if (S2)
        stage2(Bq, bn + 128, (T + 2) * BK2, lds + pB1, sr0, sc0, sr1, sc1, t16);
    __builtin_amdgcn_s_barrier();
    __builtin_amdgcn_s_setprio(1);
    #pragma unroll
    for (int fm = 0; fm < 4; ++fm)
        #pragma unroll
        for (int fn = 0; fn < 2; ++fn)
            #pragma unroll
            for (int ks = 0; ks < 2; ++ks)
                acc[1][0][fm][fn] = __builtin_amdgcn_mfma_f32_16x16x32_bf16(
                    a[fm][ks], b0[fn][ks], acc[1][0][fm][fn], 0, 0, 0);
    __builtin_amdgcn_s_setprio(0);
    vmwait<WNEXT>();
    __builtin_amdgcn_s_barrier();
}

__global__ __launch_bounds__(512, 2)
void gemm_hinge(const unsigned short* __restrict__ A,
                const unsigned short* __restrict__ Bq,
                const float* __restrict__ pos,
                float* __restrict__ out) {
    __shared__ __align__(16) unsigned char lds[131072];

    const int tid  = threadIdx.x;
    const int lane = tid & 63;
    const int wave = tid >> 6;

    // XCD swizzle: grid 512 = 16 bm-tiles x 32 bn-tiles; each XCD gets an
    // 8x8 square of tiles (4 MB A-panel + 4 MB B-panel working set).
    const int bid = blockIdx.x;
    const int x   = bid & 7;           // XCD (dispatch round-robin)
    const int idx = bid >> 3;          // 0..63 within XCD chunk
    const int bm = ((x & 1) * 8 + (idx & 7)) * 256;
    const int bn = ((x >> 1) * 8 + (idx >> 3)) * 256;

    const int wr = wave >> 2, wc = wave & 3;
    const int ln15 = lane & 15, kq = lane >> 4;
    // swizzled read addresses for ks=0/1 (XOR hits byte bits[6:4])
    const int amask = (ln15 & 7) << 4;
    const int aL0 = (ln15 * 128 + kq * 16) ^ amask;
    const int aL1 = (ln15 * 128 + 64 + kq * 16) ^ amask;
    const int t16 = tid * 16;
    const int d0 = t16, d1 = t16 + 8192;
    const int l0 = d0 ^ (((d0 >> 7) & 7) << 4);
    const int l1 = d1 ^ (((d1 >> 7) & 7) << 4);
    const int sr0 = l0 >> 7, sc0 = (l0 & 127) >> 1;
    const int sr1 = l1 >> 7, sc1 = (l1 & 127) >> 1;

    f32x4 acc[2][2][4][2];
    #pragma unroll
    for (int a = 0; a < 2; ++a)
        #pragma unroll
        for (int b = 0; b < 2; ++b)
            #pragma unroll
            for (int c = 0; c < 4; ++c)
                #pragma unroll
                for (int d = 0; d < 2; ++d)
                    acc[a][b][c][d] = (f32x4){0.f, 0.f, 0.f, 0.f};

    // prologue: per-thread issue order 0.Ah0, 0.Bh0, 0.Bh1, 0.Ah1, 1.Ah0, 1.Bh0, 1.Bh1
    stage2(A,  bm,       0,   lds,                         sr0, sc0, sr1, sc1, t16);
    stage2(Bq, bn,       0,   lds + 65536,                 sr0, sc0, sr1, sc1, t16);
    stage2(Bq, bn + 128, 0,   lds + 65536 + 16384,         sr0, sc0, sr1, sc1, t16);
    stage2(A,  bm + 128, 0,   lds + 16384,                 sr0, sc0, sr1, sc1, t16);
    stage2(A,  bm,       BK2, lds + 32768,                 sr0, sc0, sr1, sc1, t16);
    stage2(Bq, bn,       BK2, lds + 65536 + 32768,         sr0, sc0, sr1, sc1, t16);
    stage2(Bq, bn + 128, BK2, lds + 65536 + 32768 + 16384, sr0, sc0, sr1, sc1, t16);
    vmwait<10>();                       // 0.Ah0 + 0.Bh0 landed
    __builtin_amdgcn_s_barrier();

    #pragma unroll 1
    for (int T = 0; T < 14; ++T)
        gemm_window<true, true, 10, 10, 10>(T, lds, A, Bq, bm, bn, wr, wc, aL0, aL1,
                                            sr0, sc0, sr1, sc1, t16, acc);
    gemm_window<true, false, 10, 8, 4>(14, lds, A, Bq, bm, bn, wr, wc, aL0, aL1,
                                       sr0, sc0, sr1, sc1, t16, acc);
    gemm_window<false, false, 2, 0, 0>(15, lds, A, Bq, bm, bn, wr, wc, aL0, aL1,
                                       sr0, sc0, sr1, sc1, t16, acc);

    // ---- fused hinge epilogue ----
    // C/D: col = bn + nh*128 + wc*32 + fn*16 + (lane&15); row = bm + mh*128 + wr*64 + fm*16 + kq*4 + j
    float lsum = 0.f;
    const int rj = kq * 4;
    #pragma unroll
    for (int mh = 0; mh < 2; ++mh)
        #pragma unroll
        for (int fm = 0; fm < 4; ++fm) {
            const float4 p4 = *reinterpret_cast<const float4*>(
                pos + bm + mh * 128 + wr * 64 + fm * 16 + rj);
            const float pj[4] = {p4.x, p4.y, p4.z, p4.w};
            #pragma unroll
            for (int nh = 0; nh < 2; ++nh)
                #pragma unroll
                for (int fn = 0; fn < 2; ++fn)
                    #pragma unroll
                    for (int j = 0; j < 4; ++j)
                        lsum += fmaxf(DELTA_M - pj[j] + acc[mh][nh][fm][fn][j], 0.f);
        }
    #pragma unroll
    for (int off = 32; off; off >>= 1) lsum += __shfl_down(lsum, off);
    __syncthreads();                    // LDS safe to reuse (all tiles consumed)
    float* red = reinterpret_cast<float*>(lds);
    if (lane == 0) red[wave] = lsum;
    __syncthreads();
    if (tid == 0) {
        float s = 0.f;
        #pragma unroll
        for (int w = 0; w < 8; ++w) s += red[w];
        atomicAdd(out, s);
    }
}

extern "C" void kernel_launch(void* const* d_in, const int* in_sizes, int n_in,
                              void* d_out, int out_size, void* d_ws, size_t ws_size,
                              hipStream_t stream) {
    const float* q     = (const float*)d_in[0];
    const float* k     = (const float*)d_in[1];
    const float* queue = (const float*)d_in[2];
    float* out = (float*)d_out;

    unsigned short* qn  = (unsigned short*)d_ws;
    unsigned short* qun = qn + (size_t)B_ROWS * DDIM;
    float* pos = (float*)(qun + (size_t)N_ROWS * DDIM);

    hipMemsetAsync(d_out, 0, sizeof(float), stream);
    norm_kernel<<<(B_ROWS + N_ROWS) / 4, 256, 0, stream>>>(q, k, queue, qn, qun, pos);
    gemm_hinge<<<(B_ROWS / 256) * (N_ROWS / 256), 512, 0, stream>>>(qn, qun, pos, out);
}